// Round 3
// baseline (405.205 us; speedup 1.0000x reference)
//
#include <hip/hip_runtime.h>

// Problem constants (fixed by the reference)
#define MM 8192
#define NN 4096
#define KK 4096

// GEMM tiling: block 128x256, BK=128, 4 waves in 2x2, wave tile 64x128.
// Rationale (R3): 4x8 acc grid per wave -> each A-frag feeds 8 MFMAs, each
// B-frag 4 -> LDS-read bytes per MFMA drop from 8 to 6 B/lane, lifting the
// LDS-read-BW MfmaUtil ceiling from ~57% to ~77% (256 B/cyc/CU port).
#define BM 128
#define BN 256
#define BK 128

typedef int int32x4 __attribute__((ext_vector_type(4)));

// ---------------------------------------------------------------------------
// Async global->LDS, 16B per lane. LDS destination is wave-uniform base +
// lane*16 (m104/m108); global source address is per-lane free.
// ---------------------------------------------------------------------------
__device__ __forceinline__ void async_load16(const void* g, void* l) {
  __builtin_amdgcn_global_load_lds(
      (__attribute__((address_space(1))) void*)(void*)g,
      (__attribute__((address_space(3))) void*)l,
      16, 0, 0);
}

// ---------------------------------------------------------------------------
// Pack kernel: int32 (int8-range) -> int8, subtracting zero points.
// 4 elements/thread: one int4 load (wave reads 1 KB contiguous), one 4B store
// (wave writes 256B contiguous).  A/W boundary is block-aligned.
// ---------------------------------------------------------------------------
__global__ __launch_bounds__(256) void pack_kernel(
    const int* __restrict__ a, const int* __restrict__ w,
    char* __restrict__ a8, char* __restrict__ w8,
    const int* __restrict__ izp, const int* __restrict__ wzp) {
  const long tid = (long)blockIdx.x * 256 + threadIdx.x;
  const long A_T = (long)MM * KK / 4;

  const int4* src;
  int* dst;
  int z;
  if (tid < A_T) {
    src = (const int4*)a + tid;
    dst = (int*)a8 + tid;
    z = izp[0];
  } else {
    long t = tid - A_T;
    src = (const int4*)w + t;
    dst = (int*)w8 + t;
    z = wzp[t >> 10];  // K/4 = 1024 threads per weight row
  }

  int4 v = *src;
  union { char c[4]; int q; } u;
  u.c[0] = (char)(v.x - z);
  u.c[1] = (char)(v.y - z);
  u.c[2] = (char)(v.z - z);
  u.c[3] = (char)(v.w - z);
  *dst = u.q;
}

// ---------------------------------------------------------------------------
// int8 GEMM: C[m][n] = sum_k A8[m][k] * W8[n][k], epilogue
//   out = is * ws[n] * C + bias[n]   (fp32)
//
// LDS rows are 128B = exactly 32 banks; swizzle: physical 16B sub-chunk p of
// row r holds logical p ^ (r&7), applied for free via the per-lane *global*
// source address of global_load_lds. R2 measured SQ_LDS_BANK_CONFLICT == 0
// with this scheme — keep the math identical (row stride unchanged).
// ---------------------------------------------------------------------------
__global__ __launch_bounds__(256, 2) void qgemm_kernel(
    const char* __restrict__ A8, const char* __restrict__ W8,
    float* __restrict__ out,
    const float* __restrict__ bias,
    const float* __restrict__ is_ptr,
    const float* __restrict__ wscale) {
  __shared__ __attribute__((aligned(16))) char As[BM * BK];  // 16 KB
  __shared__ __attribute__((aligned(16))) char Bs[BN * BK];  // 32 KB

  // ---- block swizzle ----------------------------------------------------
  // grid = 64 m-tiles * 16 n-tiles = 1024 blocks; pid%8 -> XCD (round-robin
  // dispatch heuristic). Each XCD owns bn in {2x, 2x+1} x all 64 bm: its B
  // working set is 2 tiles * 256 cols * 4096 B = 2 MB -> L2-resident; A
  // (33.5 MB) streams from L3.
  const int pid = blockIdx.x;
  const int xcd = pid & 7;
  const int i   = pid >> 3;            // 0..127
  const int bn  = xcd * 2 + (i >> 6);  // 0..15
  const int bm  = i & 63;              // 0..63

  const int tid  = threadIdx.x;
  const int wave = tid >> 6;
  const int lane = tid & 63;
  const int wm = (wave >> 1) * 64;    // wave tile origin: 2x2 grid of 64x128
  const int wn = (wave & 1) * 128;

  // ---- staging ----------------------------------------------------------
  // Chunks of 1 KB = 8 rows. As: 16 chunks, Bs: 32 chunks. Wave w stages A
  // chunks {w+4j, j<4} and B chunks {w+4j, j<8} = 12 async loads / iter.
  // Lane l -> row_in_chunk = l>>3, physical sub = l&7, logical sub =
  // (l&7)^(l>>3)  [row&7 == l>>3].
  const int srow = lane >> 3;
  const int ssub = (lane & 7) ^ srow;
  const char* a_src[4];
  char*       a_dst[4];
  const char* b_src[8];
  char*       b_dst[8];
#pragma unroll
  for (int j = 0; j < 4; ++j) {
    const int c = wave + j * 4;
    a_src[j] = A8 + (long)(bm * BM + c * 8 + srow) * KK + ssub * 16;
    a_dst[j] = As + c * 1024;
  }
#pragma unroll
  for (int j = 0; j < 8; ++j) {
    const int c = wave + j * 4;
    b_src[j] = W8 + (long)(bn * BN + c * 8 + srow) * KK + ssub * 16;
    b_dst[j] = Bs + c * 1024;
  }

  // ---- fragment read addressing -----------------------------------------
  // MFMA 16x16x64 operand: element row = lane&15, k = (lane>>4)*16 + j.
  // LDS row R = (wm|wn) + t*16 + row_q; R&7 = row_q&7. Physical sub for
  // K-half h: (h*4 + quad) ^ (row_q&7).
  const int row_q = lane & 15;
  const int quad  = lane >> 4;
  const int psub0 = quad ^ (row_q & 7);
  const int psub1 = psub0 ^ 4;
  const char* a_rd = As + (wm + row_q) * BK;
  const char* b_rd = Bs + (wn + row_q) * BK;

  int32x4 acc[4][8];
#pragma unroll
  for (int mi = 0; mi < 4; ++mi)
#pragma unroll
    for (int ni = 0; ni < 8; ++ni) acc[mi][ni] = (int32x4)0;

  for (int kk = 0; kk < KK; kk += BK) {
#pragma unroll
    for (int j = 0; j < 4; ++j) async_load16(a_src[j] + kk, a_dst[j]);
#pragma unroll
    for (int j = 0; j < 8; ++j) async_load16(b_src[j] + kk, b_dst[j]);
    __syncthreads();  // vmcnt(0) drain + barrier

#pragma unroll
    for (int h = 0; h < 2; ++h) {
      const int ps = (h == 0) ? psub0 : psub1;
      int32x4 afrag[4], bfrag[8];
#pragma unroll
      for (int mi = 0; mi < 4; ++mi)
        afrag[mi] = *(const int32x4*)(a_rd + mi * 16 * BK + ps * 16);
#pragma unroll
      for (int ni = 0; ni < 8; ++ni)
        bfrag[ni] = *(const int32x4*)(b_rd + ni * 16 * BK + ps * 16);

#pragma unroll
      for (int mi = 0; mi < 4; ++mi)
#pragma unroll
        for (int ni = 0; ni < 8; ++ni)
          acc[mi][ni] = __builtin_amdgcn_mfma_i32_16x16x64_i8(
              afrag[mi], bfrag[ni], acc[mi][ni], 0, 0, 0);
    }

    __syncthreads();
  }

  // ---- epilogue: out = is * ws[n] * acc + bias[n] -----------------------
  // C/D layout (16x16): col = lane&15, row = (lane>>4)*4 + reg
  const float is0 = is_ptr[0];
  const int row_base = bm * BM + wm + quad * 4;
  const int col_base = bn * BN + wn + row_q;
#pragma unroll
  for (int ni = 0; ni < 8; ++ni) {
    const int col = col_base + ni * 16;
    const float s = is0 * wscale[col];
    const float b = bias[col];
#pragma unroll
    for (int mi = 0; mi < 4; ++mi) {
      const int row = row_base + mi * 16;
#pragma unroll
      for (int r = 0; r < 4; ++r) {
        out[(long)(row + r) * NN + col] = (float)acc[mi][ni][r] * s + b;
      }
    }
  }
}

// ---------------------------------------------------------------------------
extern "C" void kernel_launch(void* const* d_in, const int* in_sizes, int n_in,
                              void* d_out, int out_size, void* d_ws, size_t ws_size,
                              hipStream_t stream) {
  const int*   inp    = (const int*)d_in[0];    // [M,K] int32 (int8-range)
  const int*   weight = (const int*)d_in[1];    // [N,K] int32 (int8-range)
  const float* bias   = (const float*)d_in[2];  // [N]
  const float* iscale = (const float*)d_in[3];  // [1]
  const int*   izp    = (const int*)d_in[4];    // [1]
  const float* wscale = (const float*)d_in[5];  // [N]
  const int*   wzp    = (const int*)d_in[6];    // [N]
  float* out = (float*)d_out;

  char* a8 = (char*)d_ws;                        // M*K  = 33.5 MB
  char* w8 = a8 + (size_t)MM * KK;               // N*K  = 16.8 MB (total 50.3 MB)

  // pack: (M*K + N*K)/4 threads = 12,582,912 -> 49152 blocks of 256 (exact)
  pack_kernel<<<49152, 256, 0, stream>>>(inp, weight, a8, w8, izp, wzp);

  // GEMM: 64 m-tiles * 16 n-tiles = 1024 blocks of 256
  qgemm_kernel<<<1024, 256, 0, stream>>>(a8, w8, out, bias, iscale, wscale);
}